// Round 1
// baseline (5812.547 us; speedup 1.0000x reference)
//
#include <hip/hip_runtime.h>
#include <math.h>

// ---------------- problem constants ----------------
#define PH   4
#define CHN  8
#define ZT   8
#define ZE   6          // effective z slices: z in [1,7)
#define HG   320
#define WG   320
#define HW2  102400     // 320*320
#define NKP  4096
#define LSTR 321        // LDS line stride (pad +1)

constexpr float GAMMA_C = 0.1f;
constexpr float TAU_C   = 0.2f;
constexpr float EPS_C   = 0.01f;
constexpr float INV_N   = 1.0f / 786432.0f;   // PH*CHN*ZE*NKP
#define TWO_PI_F 6.28318530717958647692f

// ---------------- complex helpers ----------------
__device__ __forceinline__ float2 cmul(float2 a, float2 b){
  return make_float2(a.x*b.x - a.y*b.y, a.x*b.y + a.y*b.x);
}
__device__ __forceinline__ void cmac(float2& d, float2 a, float2 b){
  d.x = fmaf(a.x, b.x, fmaf(-a.y, b.y, d.x));
  d.y = fmaf(a.x, b.y, fmaf( a.y, b.x, d.y));
}

__device__ __forceinline__ void corners(float gy, float gx, int& y0, int& x0, int& y1, int& x1,
                                        float& w00, float& w01, float& w10, float& w11){
  float y0f = floorf(gy), x0f = floorf(gx);
  float wy = gy - y0f, wx = gx - x0f;
  y0 = (int)y0f; x0 = (int)x0f;
  y1 = min(y0 + 1, HG - 1); x1 = min(x0 + 1, WG - 1);
  w00 = (1.f - wy) * (1.f - wx);
  w01 = (1.f - wy) * wx;
  w10 = wy * (1.f - wx);
  w11 = wy * wx;
}

// ---------------- 320-pt FFT: 16 lines per block, 4-step N1=20 x N2=16 ----------------
// X[k2 + 16*k1] = sum_{n1<20} W20^{n1 k1} * W320^{n1 k2} * ( sum_{n2<16} x[n1 + 20 n2] W16^{n2 k2} )
// Forward DFT twiddles (e^{-2pi i}). The backward/transpose pass uses the SAME direction
// (formal transpose of the symmetric DFT matrix), matching JAX's bilinear VJP convention.
__device__ __forceinline__ void init_w320(float2* w320, int tid){
  for (int i = tid; i < 320; i += 256){
    float ang = -TWO_PI_F * (float)i / 320.0f;
    float s, c;
    sincosf(ang, &s, &c);
    w320[i] = make_float2(c, s);
  }
}

__device__ void fft320_lines(float2* __restrict__ ld, const float2* __restrict__ w320, int tid){
  // step 1: tasks (line, n1), 16*20 = 320 tasks. In-place safe per task (read set == write set).
  for (int task = tid; task < 320; task += 256){
    int line = task / 20;
    int n1   = task - line * 20;
    float2* L = ld + line * LSTR;
    float2 a[16];
    #pragma unroll
    for (int n2 = 0; n2 < 16; n2++) a[n2] = L[n1 + 20 * n2];
    #pragma unroll
    for (int k2 = 0; k2 < 16; k2++){
      float2 acc = make_float2(0.f, 0.f);
      #pragma unroll
      for (int n2 = 0; n2 < 16; n2++) cmac(acc, a[n2], w320[20 * ((n2 * k2) & 15)]);
      acc = cmul(acc, w320[n1 * k2]);        // inter-stage twiddle W320^{n1*k2} (<=285)
      L[n1 + 20 * k2] = acc;
    }
  }
  __syncthreads();
  // step 2: tasks (line, k2), 16*16 = 256 tasks. Load->barrier->store (write set differs).
  {
    int line = tid >> 4;
    int k2   = tid & 15;
    float2* L = ld + line * LSTR;
    float2 b[20];
    #pragma unroll
    for (int n1 = 0; n1 < 20; n1++) b[n1] = L[n1 + 20 * k2];
    __syncthreads();
    #pragma unroll
    for (int k1 = 0; k1 < 20; k1++){
      float2 acc = make_float2(0.f, 0.f);
      #pragma unroll
      for (int n1 = 0; n1 < 20; n1++) cmac(acc, b[n1], w320[16 * ((n1 * k1) % 20)]);
      L[k2 + 16 * k1] = acc;
    }
  }
  __syncthreads();
}

// ---------------- kernels ----------------
__global__ __launch_bounds__(256) void k_init(const float2* __restrict__ img0, float2* __restrict__ x, int n){
  int i = blockIdx.x * 256 + threadIdx.x;
  if (i < n){
    float2 v = img0[i];
    v.x = isnan(v.x) ? 0.f : fminf(fmaxf(v.x, -3.4028235e38f), 3.4028235e38f);
    v.y = isnan(v.y) ? 0.f : fminf(fmaxf(v.y, -3.4028235e38f), 3.4028235e38f);
    x[i] = v;
  }
}

__global__ __launch_bounds__(256) void k_warp(const float2* __restrict__ x, const float* __restrict__ mvf,
                                              float2* __restrict__ warped){
  int gid = blockIdx.x * 256 + threadIdx.x;          // over PH*ZE*HW2
  int hw = gid % HW2;
  int pz = gid / HW2;
  int zz = pz % ZE, p = pz / ZE, z = zz + 1;
  int h = hw / WG, w = hw - h * WG;
  const float* mv = mvf + ((size_t)(p * 2 + 0) * ZT + z) * HW2;
  float fy = mv[hw];
  float fx = mv[(size_t)ZT * HW2 + hw];
  float gy = fminf(fmaxf((float)h + fy, 0.f), 319.f);
  float gx = fminf(fmaxf((float)w + fx, 0.f), 319.f);
  int y0, x0, y1, x1; float w00, w01, w10, w11;
  corners(gy, gx, y0, x0, y1, x1, w00, w01, w10, w11);
  const float2* xs = x + (size_t)(p * ZT + z) * HW2;
  float2 v00 = xs[y0 * WG + x0], v01 = xs[y0 * WG + x1];
  float2 v10 = xs[y1 * WG + x0], v11 = xs[y1 * WG + x1];
  float2 o;
  o.x = v00.x * w00 + v01.x * w01 + v10.x * w10 + v11.x * w11;
  o.y = v00.y * w00 + v01.y * w01 + v10.y * w10 + v11.y * w11;
  warped[gid] = o;
}

// row FFT forward, fused: in = warped*csm*(-1)^(h+w)
__global__ __launch_bounds__(256) void k_fft_row_fwd(const float2* __restrict__ warped, const float2* __restrict__ csm,
                                                     float2* __restrict__ F, int p){
  __shared__ float2 ld[16 * LSTR];
  __shared__ float2 w320[320];
  int tid = threadIdx.x;
  init_w320(w320, tid);
  int bid = blockIdx.x;                     // c*120 + zz*20 + rg
  int rg = bid % 20; int t = bid / 20; int zz = t % ZE; int c = t / ZE; int z = zz + 1;
  const float2* wr = warped + ((size_t)(p * ZE + zz)) * HW2 + (size_t)rg * 16 * WG;
  const float2* cs = csm + ((size_t)(c * ZT + z)) * HW2 + (size_t)rg * 16 * WG;
  for (int i = tid; i < 16 * WG; i += 256){
    int line = i / WG; int w = i - line * WG;
    float2 v = cmul(wr[i], cs[i]);
    int h = rg * 16 + line;
    float sgn = ((h + w) & 1) ? -1.f : 1.f;
    ld[line * LSTR + w] = make_float2(v.x * sgn, v.y * sgn);
  }
  __syncthreads();
  fft320_lines(ld, w320, tid);
  float2* out = F + ((size_t)(c * ZE + zz)) * HW2 + (size_t)rg * 16 * WG;
  for (int i = tid; i < 16 * WG; i += 256){
    int line = i / WG; int w = i - line * WG;
    out[i] = ld[line * LSTR + w];
  }
}

// column FFT, in place (used in both forward and transpose passes)
__global__ __launch_bounds__(256) void k_fft_col(float2* __restrict__ F){
  __shared__ float2 ld[16 * LSTR];
  __shared__ float2 w320[320];
  int tid = threadIdx.x;
  init_w320(w320, tid);
  int bid = blockIdx.x;                     // slice*20 + cg, slice = c*ZE+zz
  int cg = bid % 20; int s = bid / 20;
  float2* Fs = F + (size_t)s * HW2 + cg * 16;
  for (int i = tid; i < 5120; i += 256){
    int h = i >> 4; int col = i & 15;
    ld[col * LSTR + h] = Fs[h * WG + col];
  }
  __syncthreads();
  fft320_lines(ld, w320, tid);
  for (int i = tid; i < 5120; i += 256){
    int h = i >> 4; int col = i & 15;
    Fs[h * WG + col] = ld[col * LSTR + h];
  }
}

__global__ __launch_bounds__(256) void k_sample(const float2* __restrict__ F, const float* __restrict__ traj,
                                                float2* __restrict__ est, unsigned int* __restrict__ dmax, int p){
  int gid = blockIdx.x * 256 + threadIdx.x;     // over CHN*ZE*NKP
  int k = gid & (NKP - 1);
  int t = gid >> 12;
  int zz = t % ZE; int c = t / ZE;
  float ty = traj[(p * 2 + 0) * NKP + k];
  float tx = traj[(p * 2 + 1) * NKP + k];
  float gy = fminf(fmaxf((ty / TWO_PI_F + 0.5f) * 320.f, 0.f), 319.f);
  float gx = fminf(fmaxf((tx / TWO_PI_F + 0.5f) * 320.f, 0.f), 319.f);
  int y0, x0, y1, x1; float w00, w01, w10, w11;
  corners(gy, gx, y0, x0, y1, x1, w00, w01, w10, w11);
  const float2* Fs = F + (size_t)(c * ZE + zz) * HW2;
  float2 v00 = Fs[y0 * WG + x0], v01 = Fs[y0 * WG + x1];
  float2 v10 = Fs[y1 * WG + x0], v11 = Fs[y1 * WG + x1];
  float2 e;
  e.x = v00.x * w00 + v01.x * w01 + v10.x * w10 + v11.x * w11;
  e.y = v00.y * w00 + v01.y * w01 + v10.y * w10 + v11.y * w11;
  est[((size_t)(p * CHN + c) * ZE + zz) * NKP + k] = e;
  float d2 = e.x * e.x + e.y * e.y;
  for (int off = 32; off > 0; off >>= 1) d2 = fmaxf(d2, __shfl_down(d2, off, 64));
  if ((threadIdx.x & 63) == 0) atomicMax(dmax, __float_as_uint(d2));   // d2 >= 0: uint order ok
}

// est -> cotangent: G = (w^2/N) * conj(est - y)   (conj = JAX bilinear-VJP convention)
__global__ __launch_bounds__(256) void k_weights(float2* __restrict__ est, const float2* __restrict__ kdata,
                                                 const unsigned int* __restrict__ dmax){
  int gid = blockIdx.x * 256 + threadIdx.x;     // over PH*CHN*ZE*NKP
  int k = gid & (NKP - 1);
  int t = gid >> 12;                            // (p*CHN+c)*ZE + zz
  int zz = t % ZE; int pc = t / ZE; int z = zz + 1;
  float md = sqrtf(__uint_as_float(*dmax));
  float2 e = est[gid];
  float det = sqrtf(e.x * e.x + e.y * e.y);
  float wv = 1.0f / (det / md + EPS_C);
  float sc = wv * wv * INV_N;
  float2 y = kdata[((size_t)pc * ZT + z) * NKP + k];
  est[gid] = make_float2(sc * (e.x - y.x), -sc * (e.y - y.y));
}

__global__ __launch_bounds__(256) void k_scatter(const float2* __restrict__ G, const float* __restrict__ traj,
                                                 float* __restrict__ F, int p){
  int gid = blockIdx.x * 256 + threadIdx.x;     // over CHN*ZE*NKP
  int k = gid & (NKP - 1);
  int t = gid >> 12;
  int zz = t % ZE; int c = t / ZE;
  float ty = traj[(p * 2 + 0) * NKP + k];
  float tx = traj[(p * 2 + 1) * NKP + k];
  float gy = fminf(fmaxf((ty / TWO_PI_F + 0.5f) * 320.f, 0.f), 319.f);
  float gx = fminf(fmaxf((tx / TWO_PI_F + 0.5f) * 320.f, 0.f), 319.f);
  int y0, x0, y1, x1; float w00, w01, w10, w11;
  corners(gy, gx, y0, x0, y1, x1, w00, w01, w10, w11);
  float2 g = G[((size_t)(p * CHN + c) * ZE + zz) * NKP + k];
  float* Fs = F + (size_t)(c * ZE + zz) * HW2 * 2;
  atomicAdd(&Fs[(y0 * WG + x0) * 2 + 0], g.x * w00); atomicAdd(&Fs[(y0 * WG + x0) * 2 + 1], g.y * w00);
  atomicAdd(&Fs[(y0 * WG + x1) * 2 + 0], g.x * w01); atomicAdd(&Fs[(y0 * WG + x1) * 2 + 1], g.y * w01);
  atomicAdd(&Fs[(y1 * WG + x0) * 2 + 0], g.x * w10); atomicAdd(&Fs[(y1 * WG + x0) * 2 + 1], g.y * w10);
  atomicAdd(&Fs[(y1 * WG + x1) * 2 + 0], g.x * w11); atomicAdd(&Fs[(y1 * WG + x1) * 2 + 1], g.y * w11);
}

// transpose row pass, fused epilogue: *(-1)^(h+w), *csm (NO conj: formal transpose), sum over coils
__global__ __launch_bounds__(256) void k_fft_row_bwd(const float2* __restrict__ F, const float2* __restrict__ csm,
                                                     float2* __restrict__ gwarped, int p){
  __shared__ float2 ld[16 * LSTR];
  __shared__ float2 w320[320];
  int tid = threadIdx.x;
  init_w320(w320, tid);
  int bid = blockIdx.x;                    // zz*160 + rp
  int rp = bid % 160; int zz = bid / 160; int z = zz + 1;
  for (int i = tid; i < 16 * WG; i += 256){
    int line = i / WG; int w = i - line * WG;
    int c = line & 7; int hh = line >> 3;
    ld[line * LSTR + w] = F[((size_t)(c * ZE + zz)) * HW2 + (size_t)(rp * 2 + hh) * WG + w];
  }
  __syncthreads();
  fft320_lines(ld, w320, tid);
  for (int i = tid; i < 2 * WG; i += 256){
    int hh = i / WG; int w = i - hh * WG;
    int h = rp * 2 + hh;
    float2 acc = make_float2(0.f, 0.f);
    #pragma unroll
    for (int c = 0; c < 8; c++){
      float2 u  = ld[(hh * 8 + c) * LSTR + w];
      float2 cv = csm[((size_t)(c * ZT + z)) * HW2 + (size_t)h * WG + w];
      cmac(acc, u, cv);
    }
    float sgn = ((h + w) & 1) ? -1.f : 1.f;
    gwarped[((size_t)(p * ZE + zz)) * HW2 + (size_t)h * WG + w] = make_float2(acc.x * sgn, acc.y * sgn);
  }
}

__global__ __launch_bounds__(256) void k_warpadj(const float2* __restrict__ gw, const float* __restrict__ mvf,
                                                 float* __restrict__ gdc){
  int gid = blockIdx.x * 256 + threadIdx.x;     // PH*ZE*HW2
  int hw = gid % HW2;
  int pz = gid / HW2;
  int zz = pz % ZE, p = pz / ZE, z = zz + 1;
  int h = hw / WG, w = hw - h * WG;
  const float* mv = mvf + ((size_t)(p * 2 + 0) * ZT + z) * HW2;
  float fy = mv[hw];
  float fx = mv[(size_t)ZT * HW2 + hw];
  float gy = fminf(fmaxf((float)h + fy, 0.f), 319.f);
  float gx = fminf(fmaxf((float)w + fx, 0.f), 319.f);
  int y0, x0, y1, x1; float w00, w01, w10, w11;
  corners(gy, gx, y0, x0, y1, x1, w00, w01, w10, w11);
  float2 g = gw[gid];
  float* gs = gdc + (size_t)pz * HW2 * 2;
  atomicAdd(&gs[(y0 * WG + x0) * 2 + 0], g.x * w00); atomicAdd(&gs[(y0 * WG + x0) * 2 + 1], g.y * w00);
  atomicAdd(&gs[(y0 * WG + x1) * 2 + 0], g.x * w01); atomicAdd(&gs[(y0 * WG + x1) * 2 + 1], g.y * w01);
  atomicAdd(&gs[(y1 * WG + x0) * 2 + 0], g.x * w10); atomicAdd(&gs[(y1 * WG + x0) * 2 + 1], g.y * w10);
  atomicAdd(&gs[(y1 * WG + x1) * 2 + 0], g.x * w11); atomicAdd(&gs[(y1 * WG + x1) * 2 + 1], g.y * w11);
}

// TV gradient (natural real-pair grad), stored CONJUGATED to match jax.grad convention
__global__ __launch_bounds__(256) void k_tv(const float2* __restrict__ x, float2* __restrict__ gtv){
  int gid = blockIdx.x * 256 + threadIdx.x;     // PH*ZE*HW2
  int hw = gid % HW2;
  int pz = gid / HW2;
  int zz = pz % ZE, p = pz / ZE, z = zz + 1;
  int h = hw / WG, w = hw - h * WG;
  const float2* xs = x + (size_t)(p * ZT + z) * HW2;
  float2 xc = xs[hw];
  float tre = 0.f, tim = 0.f;
  if (h > 0){
    float2 n = xs[hw - WG];
    float dr = xc.x - n.x, di = xc.y - n.y;
    float r = sqrtf(dr * dr + di * di + 1e-8f);
    tre += dr / r; tim += di / r;
  }
  if (h < HG - 1){
    float2 n = xs[hw + WG];
    float dr = n.x - xc.x, di = n.y - xc.y;
    float r = sqrtf(dr * dr + di * di + 1e-8f);
    tre -= dr / r; tim -= di / r;
  }
  if (w > 0){
    float2 n = xs[hw - 1];
    float dr = xc.x - n.x, di = xc.y - n.y;
    float r = sqrtf(dr * dr + di * di + 1e-8f);
    tre += dr / r; tim += di / r;
  }
  if (w < WG - 1){
    float2 n = xs[hw + 1];
    float dr = n.x - xc.x, di = n.y - xc.y;
    float r = sqrtf(dr * dr + di * di + 1e-8f);
    tre -= dr / r; tim -= di / r;
  }
  gtv[gid] = make_float2(tre, -tim);
}

__global__ __launch_bounds__(256) void k_update(float2* __restrict__ x, const float2* __restrict__ gdc,
                                                const float2* __restrict__ gtv, const float* __restrict__ stdp){
  int gid = blockIdx.x * 256 + threadIdx.x;     // PH*ZE*HW2
  int hw = gid % HW2;
  int pz = gid / HW2;
  int zz = pz % ZE, p = pz / ZE;
  float s = stdp[0];
  size_t xi = (size_t)(p * ZT + zz + 1) * HW2 + hw;
  float2 xv = x[xi];
  float2 gd = gdc[gid], gt = gtv[gid];
  xv.x -= GAMMA_C * gd.x + TAU_C * s * gt.x;
  xv.y -= GAMMA_C * gd.y + TAU_C * s * gt.y;
  x[xi] = xv;
}

// ---------------- host ----------------
extern "C" void kernel_launch(void* const* d_in, const int* in_sizes, int n_in,
                              void* d_out, int out_size, void* d_ws, size_t ws_size,
                              hipStream_t stream) {
  const float2* kdata = (const float2*)d_in[0];   // (PH,CHN,ZT,NK) complex
  const float*  traj  = (const float*) d_in[1];   // (PH,2,NK)
  const float2* img0  = (const float2*)d_in[2];   // (PH,ZT,H,W) complex
  const float*  mvf   = (const float*) d_in[3];   // (PH,2,ZT,H,W)
  const float2* csm   = (const float2*)d_in[4];   // (CHN,ZT,H,W) complex
  const float*  stdp  = (const float*) d_in[5];   // (1,)
  float2* x = (float2*)d_out;                     // x lives in d_out (same layout as output)

  // workspace layout (bytes): total ~85 MB
  char* ws = (char*)d_ws;
  const size_t F_B  = (size_t)CHN * ZE * HW2 * 8;        // 39,321,600
  const size_t W_B  = (size_t)PH * ZE * HW2 * 8;         // 19,660,800
  const size_t E_B  = (size_t)PH * CHN * ZE * NKP * 8;   //  6,291,456
  float2* F      = (float2*)(ws);
  float2* warped = (float2*)(ws + F_B);                  // also reused for gwarped, then gtv
  float2* gdc    = (float2*)(ws + F_B + W_B);
  float2* est    = (float2*)(ws + F_B + 2 * W_B);
  unsigned int* dmax = (unsigned int*)(ws + F_B + 2 * W_B + E_B);

  k_init<<<12800, 256, 0, stream>>>(img0, x, PH * ZT * HW2);

  for (int it = 0; it < 3; it++){
    k_warp<<<9600, 256, 0, stream>>>(x, mvf, warped);
    hipMemsetAsync(dmax, 0, 4, stream);
    for (int p = 0; p < PH; p++){
      k_fft_row_fwd<<<960, 256, 0, stream>>>(warped, csm, F, p);
      k_fft_col    <<<960, 256, 0, stream>>>(F);
      k_sample     <<<768, 256, 0, stream>>>(F, traj, est, dmax, p);
    }
    k_weights<<<3072, 256, 0, stream>>>(est, kdata, dmax);
    for (int p = 0; p < PH; p++){
      hipMemsetAsync(F, 0, F_B, stream);
      k_scatter    <<<768, 256, 0, stream>>>(est, traj, (float*)F, p);
      k_fft_col    <<<960, 256, 0, stream>>>(F);
      k_fft_row_bwd<<<960, 256, 0, stream>>>(F, csm, warped, p);   // warped <- gwarped
    }
    hipMemsetAsync(gdc, 0, W_B, stream);
    k_warpadj<<<9600, 256, 0, stream>>>(warped, mvf, (float*)gdc);
    k_tv     <<<9600, 256, 0, stream>>>(x, warped);                // warped <- gtv
    k_update <<<9600, 256, 0, stream>>>(x, gdc, warped, stdp);
  }
}

// Round 2
// 3184.946 us; speedup vs baseline: 1.8250x; 1.8250x over previous
//
#include <hip/hip_runtime.h>
#include <math.h>

// ---------------- problem constants ----------------
#define PH   4
#define CHN  8
#define ZT   8
#define ZE   6          // effective z slices: z in [1,7)
#define HG   320
#define WG   320
#define HW2  102400     // 320*320
#define NKP  4096
#define LSTR 321        // LDS line stride (pad +1)

constexpr float GAMMA_C = 0.1f;
constexpr float TAU_C   = 0.2f;
constexpr float EPS_C   = 0.01f;
constexpr float INV_N   = 1.0f / 786432.0f;   // PH*CHN*ZE*NKP
#define TWO_PI_F 6.28318530717958647692f

// ---------------- complex helpers ----------------
__device__ __forceinline__ float2 cmul(float2 a, float2 b){
  return make_float2(a.x*b.x - a.y*b.y, a.x*b.y + a.y*b.x);
}
__device__ __forceinline__ void cmac(float2& d, float2 a, float2 b){
  d.x = fmaf(a.x, b.x, fmaf(-a.y, b.y, d.x));
  d.y = fmaf(a.x, b.y, fmaf( a.y, b.x, d.y));
}

__device__ __forceinline__ void corners(float gy, float gx, int& y0, int& x0, int& y1, int& x1,
                                        float& w00, float& w01, float& w10, float& w11){
  float y0f = floorf(gy), x0f = floorf(gx);
  float wy = gy - y0f, wx = gx - x0f;
  y0 = (int)y0f; x0 = (int)x0f;
  y1 = min(y0 + 1, HG - 1); x1 = min(x0 + 1, WG - 1);
  w00 = (1.f - wy) * (1.f - wx);
  w01 = (1.f - wy) * wx;
  w10 = wy * (1.f - wx);
  w11 = wy * wx;
}

// ---------------- 320-pt FFT: 16 lines per block, 4-step N1=20 x N2=16 ----------------
// Forward DFT twiddles (e^{-2pi i}). The backward/transpose pass uses the SAME direction
// (formal transpose of the symmetric DFT matrix), matching JAX's bilinear VJP convention.
__device__ __forceinline__ void init_w320(float2* w320, int tid){
  for (int i = tid; i < 320; i += 256){
    float ang = -TWO_PI_F * (float)i / 320.0f;
    float s, c;
    sincosf(ang, &s, &c);
    w320[i] = make_float2(c, s);
  }
}

__device__ void fft320_lines(float2* __restrict__ ld, const float2* __restrict__ w320, int tid){
  // step 1: tasks (line, n1), 16*20 = 320 tasks. In-place safe per task (read set == write set).
  for (int task = tid; task < 320; task += 256){
    int line = task / 20;
    int n1   = task - line * 20;
    float2* L = ld + line * LSTR;
    float2 a[16];
    #pragma unroll
    for (int n2 = 0; n2 < 16; n2++) a[n2] = L[n1 + 20 * n2];
    #pragma unroll
    for (int k2 = 0; k2 < 16; k2++){
      float2 acc = make_float2(0.f, 0.f);
      #pragma unroll
      for (int n2 = 0; n2 < 16; n2++) cmac(acc, a[n2], w320[20 * ((n2 * k2) & 15)]);
      acc = cmul(acc, w320[n1 * k2]);        // inter-stage twiddle W320^{n1*k2}
      L[n1 + 20 * k2] = acc;
    }
  }
  __syncthreads();
  // step 2: tasks (line, k2), 16*16 = 256 tasks. Load->barrier->store (write set differs).
  {
    int line = tid >> 4;
    int k2   = tid & 15;
    float2* L = ld + line * LSTR;
    float2 b[20];
    #pragma unroll
    for (int n1 = 0; n1 < 20; n1++) b[n1] = L[n1 + 20 * k2];
    __syncthreads();
    #pragma unroll
    for (int k1 = 0; k1 < 20; k1++){
      float2 acc = make_float2(0.f, 0.f);
      #pragma unroll
      for (int n1 = 0; n1 < 20; n1++) cmac(acc, b[n1], w320[16 * ((n1 * k1) % 20)]);
      L[k2 + 16 * k1] = acc;
    }
  }
  __syncthreads();
}

// ---------------- kernels ----------------
__global__ __launch_bounds__(256) void k_init(const float2* __restrict__ img0, float2* __restrict__ x, int n){
  int i = blockIdx.x * 256 + threadIdx.x;
  if (i < n){
    float2 v = img0[i];
    v.x = isnan(v.x) ? 0.f : fminf(fmaxf(v.x, -3.4028235e38f), 3.4028235e38f);
    v.y = isnan(v.y) ? 0.f : fminf(fmaxf(v.y, -3.4028235e38f), 3.4028235e38f);
    x[i] = v;
  }
}

__global__ __launch_bounds__(256) void k_warp(const float2* __restrict__ x, const float* __restrict__ mvf,
                                              float2* __restrict__ warped){
  int gid = blockIdx.x * 256 + threadIdx.x;          // over PH*ZE*HW2
  int hw = gid % HW2;
  int pz = gid / HW2;
  int zz = pz % ZE, p = pz / ZE, z = zz + 1;
  int h = hw / WG, w = hw - h * WG;
  const float* mv = mvf + ((size_t)(p * 2 + 0) * ZT + z) * HW2;
  float fy = mv[hw];
  float fx = mv[(size_t)ZT * HW2 + hw];
  float gy = fminf(fmaxf((float)h + fy, 0.f), 319.f);
  float gx = fminf(fmaxf((float)w + fx, 0.f), 319.f);
  int y0, x0, y1, x1; float w00, w01, w10, w11;
  corners(gy, gx, y0, x0, y1, x1, w00, w01, w10, w11);
  const float2* xs = x + (size_t)(p * ZT + z) * HW2;
  float2 v00 = xs[y0 * WG + x0], v01 = xs[y0 * WG + x1];
  float2 v10 = xs[y1 * WG + x0], v11 = xs[y1 * WG + x1];
  float2 o;
  o.x = v00.x * w00 + v01.x * w01 + v10.x * w10 + v11.x * w11;
  o.y = v00.y * w00 + v01.y * w01 + v10.y * w10 + v11.y * w11;
  warped[gid] = o;
}

// row FFT forward, fused: in = warped*csm*(-1)^(h+w)
__global__ __launch_bounds__(256) void k_fft_row_fwd(const float2* __restrict__ warped, const float2* __restrict__ csm,
                                                     float2* __restrict__ F, int p){
  __shared__ float2 ld[16 * LSTR];
  __shared__ float2 w320[320];
  int tid = threadIdx.x;
  init_w320(w320, tid);
  int bid = blockIdx.x;                     // c*120 + zz*20 + rg
  int rg = bid % 20; int t = bid / 20; int zz = t % ZE; int c = t / ZE; int z = zz + 1;
  const float2* wr = warped + ((size_t)(p * ZE + zz)) * HW2 + (size_t)rg * 16 * WG;
  const float2* cs = csm + ((size_t)(c * ZT + z)) * HW2 + (size_t)rg * 16 * WG;
  for (int i = tid; i < 16 * WG; i += 256){
    int line = i / WG; int w = i - line * WG;
    float2 v = cmul(wr[i], cs[i]);
    int h = rg * 16 + line;
    float sgn = ((h + w) & 1) ? -1.f : 1.f;
    ld[line * LSTR + w] = make_float2(v.x * sgn, v.y * sgn);
  }
  __syncthreads();
  fft320_lines(ld, w320, tid);
  float2* out = F + ((size_t)(c * ZE + zz)) * HW2 + (size_t)rg * 16 * WG;
  for (int i = tid; i < 16 * WG; i += 256){
    int line = i / WG; int w = i - line * WG;
    out[i] = ld[line * LSTR + w];
  }
}

// column FFT, in place (forward pass)
__global__ __launch_bounds__(256) void k_fft_col(float2* __restrict__ F){
  __shared__ float2 ld[16 * LSTR];
  __shared__ float2 w320[320];
  int tid = threadIdx.x;
  init_w320(w320, tid);
  int bid = blockIdx.x;                     // slice*20 + cg, slice = c*ZE+zz
  int cg = bid % 20; int s = bid / 20;
  float2* Fs = F + (size_t)s * HW2 + cg * 16;
  for (int i = tid; i < 5120; i += 256){
    int h = i >> 4; int col = i & 15;
    ld[col * LSTR + h] = Fs[h * WG + col];
  }
  __syncthreads();
  fft320_lines(ld, w320, tid);
  for (int i = tid; i < 5120; i += 256){
    int h = i >> 4; int col = i & 15;
    Fs[h * WG + col] = ld[col * LSTR + h];
  }
}

__global__ __launch_bounds__(256) void k_sample(const float2* __restrict__ F, const float* __restrict__ traj,
                                                float2* __restrict__ est, unsigned int* __restrict__ dmax, int p){
  int gid = blockIdx.x * 256 + threadIdx.x;     // over CHN*ZE*NKP
  int k = gid & (NKP - 1);
  int t = gid >> 12;
  int zz = t % ZE; int c = t / ZE;
  float ty = traj[(p * 2 + 0) * NKP + k];
  float tx = traj[(p * 2 + 1) * NKP + k];
  float gy = fminf(fmaxf((ty / TWO_PI_F + 0.5f) * 320.f, 0.f), 319.f);
  float gx = fminf(fmaxf((tx / TWO_PI_F + 0.5f) * 320.f, 0.f), 319.f);
  int y0, x0, y1, x1; float w00, w01, w10, w11;
  corners(gy, gx, y0, x0, y1, x1, w00, w01, w10, w11);
  const float2* Fs = F + (size_t)(c * ZE + zz) * HW2;
  float2 v00 = Fs[y0 * WG + x0], v01 = Fs[y0 * WG + x1];
  float2 v10 = Fs[y1 * WG + x0], v11 = Fs[y1 * WG + x1];
  float2 e;
  e.x = v00.x * w00 + v01.x * w01 + v10.x * w10 + v11.x * w11;
  e.y = v00.y * w00 + v01.y * w01 + v10.y * w10 + v11.y * w11;
  est[((size_t)(p * CHN + c) * ZE + zz) * NKP + k] = e;
  float d2 = e.x * e.x + e.y * e.y;
  for (int off = 32; off > 0; off >>= 1) d2 = fmaxf(d2, __shfl_down(d2, off, 64));
  if ((threadIdx.x & 63) == 0) atomicMax(dmax, __float_as_uint(d2));   // d2 >= 0: uint order ok
}

// est -> cotangent: G = (w^2/N) * conj(est - y)   (conj = JAX bilinear-VJP convention)
__global__ __launch_bounds__(256) void k_weights(float2* __restrict__ est, const float2* __restrict__ kdata,
                                                 const unsigned int* __restrict__ dmax){
  int gid = blockIdx.x * 256 + threadIdx.x;     // over PH*CHN*ZE*NKP
  int k = gid & (NKP - 1);
  int t = gid >> 12;                            // (p*CHN+c)*ZE + zz
  int zz = t % ZE; int pc = t / ZE; int z = zz + 1;
  float md = sqrtf(__uint_as_float(*dmax));
  float2 e = est[gid];
  float det = sqrtf(e.x * e.x + e.y * e.y);
  float wv = 1.0f / (det / md + EPS_C);
  float sc = wv * wv * INV_N;
  float2 y = kdata[((size_t)pc * ZT + z) * NKP + k];
  est[gid] = make_float2(sc * (e.x - y.x), -sc * (e.y - y.y));
}

// backward: fused { zero-grid + k-space corner scatter (LDS atomics) + column DFT^T } per 16-col group
__global__ __launch_bounds__(256) void k_fft_col_scatter(const float2* __restrict__ G, const float* __restrict__ traj,
                                                         float2* __restrict__ F, int p){
  __shared__ float2 ld[16 * LSTR];
  __shared__ float2 w320[320];
  int tid = threadIdx.x;
  init_w320(w320, tid);
  int bid = blockIdx.x;                     // s*20 + cg, s = c*ZE+zz
  int cg = bid % 20; int s = bid / 20; int zz = s % ZE; int c = s / ZE;
  for (int i = tid; i < 16 * LSTR; i += 256) ld[i] = make_float2(0.f, 0.f);
  __syncthreads();
  int cbase = cg * 16;
  const float* tyb = traj + (p * 2 + 0) * NKP;
  const float* txb = traj + (p * 2 + 1) * NKP;
  const float2* Gs = G + ((size_t)(p * CHN + c) * ZE + zz) * NKP;
  for (int k = tid; k < NKP; k += 256){
    float gy = fminf(fmaxf((tyb[k] / TWO_PI_F + 0.5f) * 320.f, 0.f), 319.f);
    float gx = fminf(fmaxf((txb[k] / TWO_PI_F + 0.5f) * 320.f, 0.f), 319.f);
    int y0, x0, y1, x1; float w00, w01, w10, w11;
    corners(gy, gx, y0, x0, y1, x1, w00, w01, w10, w11);
    float2 gv = Gs[k];
    int c0 = x0 - cbase, c1 = x1 - cbase;
    if ((unsigned)c0 < 16u){
      atomicAdd(&ld[c0 * LSTR + y0].x, gv.x * w00); atomicAdd(&ld[c0 * LSTR + y0].y, gv.y * w00);
      atomicAdd(&ld[c0 * LSTR + y1].x, gv.x * w10); atomicAdd(&ld[c0 * LSTR + y1].y, gv.y * w10);
    }
    if ((unsigned)c1 < 16u){
      atomicAdd(&ld[c1 * LSTR + y0].x, gv.x * w01); atomicAdd(&ld[c1 * LSTR + y0].y, gv.y * w01);
      atomicAdd(&ld[c1 * LSTR + y1].x, gv.x * w11); atomicAdd(&ld[c1 * LSTR + y1].y, gv.y * w11);
    }
  }
  __syncthreads();
  fft320_lines(ld, w320, tid);
  float2* Fs = F + (size_t)s * HW2 + cbase;
  for (int i = tid; i < 5120; i += 256){
    int h = i >> 4; int col = i & 15;
    Fs[h * WG + col] = ld[col * LSTR + h];
  }
}

// transpose row pass, fused epilogue: *(-1)^(h+w), *csm (NO conj: formal transpose), sum over coils
__global__ __launch_bounds__(256) void k_fft_row_bwd(const float2* __restrict__ F, const float2* __restrict__ csm,
                                                     float2* __restrict__ gwarped, int p){
  __shared__ float2 ld[16 * LSTR];
  __shared__ float2 w320[320];
  int tid = threadIdx.x;
  init_w320(w320, tid);
  int bid = blockIdx.x;                    // zz*160 + rp
  int rp = bid % 160; int zz = bid / 160; int z = zz + 1;
  for (int i = tid; i < 16 * WG; i += 256){
    int line = i / WG; int w = i - line * WG;
    int c = line & 7; int hh = line >> 3;
    ld[line * LSTR + w] = F[((size_t)(c * ZE + zz)) * HW2 + (size_t)(rp * 2 + hh) * WG + w];
  }
  __syncthreads();
  fft320_lines(ld, w320, tid);
  for (int i = tid; i < 2 * WG; i += 256){
    int hh = i / WG; int w = i - hh * WG;
    int h = rp * 2 + hh;
    float2 acc = make_float2(0.f, 0.f);
    #pragma unroll
    for (int c = 0; c < 8; c++){
      float2 u  = ld[(hh * 8 + c) * LSTR + w];
      float2 cv = csm[((size_t)(c * ZT + z)) * HW2 + (size_t)h * WG + w];
      cmac(acc, u, cv);
    }
    float sgn = ((h + w) & 1) ? -1.f : 1.f;
    gwarped[((size_t)(p * ZE + zz)) * HW2 + (size_t)h * WG + w] = make_float2(acc.x * sgn, acc.y * sgn);
  }
}

// LDS-tiled warp adjoint: block owns TR source rows; scatters into [r0-HA, r0+TR+HA) LDS tile,
// then flushes with coalesced global atomics. Out-of-window targets (P ~ 6e-5) -> direct atomics.
#define TR 32
#define HA 8
#define LROWS (TR + 2*HA)   // 48 rows; LDS = 48*320*2*4B = 122.88 KB (gfx950: <=160KB/WG)
__global__ __launch_bounds__(256) void k_warpadj(const float2* __restrict__ gw, const float* __restrict__ mvf,
                                                 float* __restrict__ gdc){
  __shared__ float lt[LROWS * WG * 2];
  int tid = threadIdx.x;
  int bid = blockIdx.x;                    // pz*10 + tile
  int tile = bid % 10; int pz = bid / 10;
  int zz = pz % ZE, p = pz / ZE, z = zz + 1;
  int r0 = tile * TR;
  for (int i = tid; i < LROWS * WG * 2; i += 256) lt[i] = 0.f;
  __syncthreads();
  const float* mvy = mvf + ((size_t)(p * 2 + 0) * ZT + z) * HW2;
  const float* mvx = mvy + (size_t)ZT * HW2;
  const float2* g = gw + (size_t)pz * HW2;
  float* gs = gdc + (size_t)pz * HW2 * 2;
  const int lo = r0 - HA;
  for (int i = tid; i < TR * WG; i += 256){
    int h = r0 + (i / WG); int w = i - (i / WG) * WG;
    int hw = h * WG + w;
    float fy = mvy[hw];
    float fx = mvx[hw];
    float gy = fminf(fmaxf((float)h + fy, 0.f), 319.f);
    float gx = fminf(fmaxf((float)w + fx, 0.f), 319.f);
    int y0, x0, y1, x1; float w00, w01, w10, w11;
    corners(gy, gx, y0, x0, y1, x1, w00, w01, w10, w11);
    float2 gv = g[hw];
    int ry0 = y0 - lo, ry1 = y1 - lo;
    if ((unsigned)ry0 < (unsigned)LROWS){
      atomicAdd(&lt[(ry0 * WG + x0) * 2 + 0], gv.x * w00); atomicAdd(&lt[(ry0 * WG + x0) * 2 + 1], gv.y * w00);
      atomicAdd(&lt[(ry0 * WG + x1) * 2 + 0], gv.x * w01); atomicAdd(&lt[(ry0 * WG + x1) * 2 + 1], gv.y * w01);
    } else {
      atomicAdd(&gs[(y0 * WG + x0) * 2 + 0], gv.x * w00); atomicAdd(&gs[(y0 * WG + x0) * 2 + 1], gv.y * w00);
      atomicAdd(&gs[(y0 * WG + x1) * 2 + 0], gv.x * w01); atomicAdd(&gs[(y0 * WG + x1) * 2 + 1], gv.y * w01);
    }
    if ((unsigned)ry1 < (unsigned)LROWS){
      atomicAdd(&lt[(ry1 * WG + x0) * 2 + 0], gv.x * w10); atomicAdd(&lt[(ry1 * WG + x0) * 2 + 1], gv.y * w10);
      atomicAdd(&lt[(ry1 * WG + x1) * 2 + 0], gv.x * w11); atomicAdd(&lt[(ry1 * WG + x1) * 2 + 1], gv.y * w11);
    } else {
      atomicAdd(&gs[(y0 * WG + x0) * 2 + 0], 0.f);  // keep branch shape trivial; real fallback below
      atomicAdd(&gs[(y1 * WG + x0) * 2 + 0], gv.x * w10); atomicAdd(&gs[(y1 * WG + x0) * 2 + 1], gv.y * w10);
      atomicAdd(&gs[(y1 * WG + x1) * 2 + 0], gv.x * w11); atomicAdd(&gs[(y1 * WG + x1) * 2 + 1], gv.y * w11);
    }
  }
  __syncthreads();
  for (int i = tid; i < LROWS * WG; i += 256){
    int rr = i / WG; int w = i - rr * WG;
    int h = lo + rr;
    if ((unsigned)h < (unsigned)HG){
      float vx = lt[i * 2 + 0], vy = lt[i * 2 + 1];
      if (vx != 0.f) atomicAdd(&gs[(h * WG + w) * 2 + 0], vx);
      if (vy != 0.f) atomicAdd(&gs[(h * WG + w) * 2 + 1], vy);
    }
  }
}

// TV gradient (natural real-pair grad), stored CONJUGATED to match jax.grad convention
__global__ __launch_bounds__(256) void k_tv(const float2* __restrict__ x, float2* __restrict__ gtv){
  int gid = blockIdx.x * 256 + threadIdx.x;     // PH*ZE*HW2
  int hw = gid % HW2;
  int pz = gid / HW2;
  int zz = pz % ZE, p = pz / ZE, z = zz + 1;
  int h = hw / WG, w = hw - h * WG;
  const float2* xs = x + (size_t)(p * ZT + z) * HW2;
  float2 xc = xs[hw];
  float tre = 0.f, tim = 0.f;
  if (h > 0){
    float2 n = xs[hw - WG];
    float dr = xc.x - n.x, di = xc.y - n.y;
    float r = sqrtf(dr * dr + di * di + 1e-8f);
    tre += dr / r; tim += di / r;
  }
  if (h < HG - 1){
    float2 n = xs[hw + WG];
    float dr = n.x - xc.x, di = n.y - xc.y;
    float r = sqrtf(dr * dr + di * di + 1e-8f);
    tre -= dr / r; tim -= di / r;
  }
  if (w > 0){
    float2 n = xs[hw - 1];
    float dr = xc.x - n.x, di = xc.y - n.y;
    float r = sqrtf(dr * dr + di * di + 1e-8f);
    tre += dr / r; tim += di / r;
  }
  if (w < WG - 1){
    float2 n = xs[hw + 1];
    float dr = n.x - xc.x, di = n.y - xc.y;
    float r = sqrtf(dr * dr + di * di + 1e-8f);
    tre -= dr / r; tim -= di / r;
  }
  gtv[gid] = make_float2(tre, -tim);
}

__global__ __launch_bounds__(256) void k_update(float2* __restrict__ x, const float2* __restrict__ gdc,
                                                const float2* __restrict__ gtv, const float* __restrict__ stdp){
  int gid = blockIdx.x * 256 + threadIdx.x;     // PH*ZE*HW2
  int hw = gid % HW2;
  int pz = gid / HW2;
  int zz = pz % ZE, p = pz / ZE;
  float s = stdp[0];
  size_t xi = (size_t)(p * ZT + zz + 1) * HW2 + hw;
  float2 xv = x[xi];
  float2 gd = gdc[gid], gt = gtv[gid];
  xv.x -= GAMMA_C * gd.x + TAU_C * s * gt.x;
  xv.y -= GAMMA_C * gd.y + TAU_C * s * gt.y;
  x[xi] = xv;
}

// ---------------- host ----------------
extern "C" void kernel_launch(void* const* d_in, const int* in_sizes, int n_in,
                              void* d_out, int out_size, void* d_ws, size_t ws_size,
                              hipStream_t stream) {
  const float2* kdata = (const float2*)d_in[0];   // (PH,CHN,ZT,NK) complex
  const float*  traj  = (const float*) d_in[1];   // (PH,2,NK)
  const float2* img0  = (const float2*)d_in[2];   // (PH,ZT,H,W) complex
  const float*  mvf   = (const float*) d_in[3];   // (PH,2,ZT,H,W)
  const float2* csm   = (const float2*)d_in[4];   // (CHN,ZT,H,W) complex
  const float*  stdp  = (const float*) d_in[5];   // (1,)
  float2* x = (float2*)d_out;                     // x lives in d_out (same layout as output)

  // workspace layout (bytes): total ~85 MB
  char* ws = (char*)d_ws;
  const size_t F_B  = (size_t)CHN * ZE * HW2 * 8;        // 39,321,600
  const size_t W_B  = (size_t)PH * ZE * HW2 * 8;         // 19,660,800
  const size_t E_B  = (size_t)PH * CHN * ZE * NKP * 8;   //  6,291,456
  float2* F      = (float2*)(ws);
  float2* warped = (float2*)(ws + F_B);                  // also reused for gwarped, then gtv
  float2* gdc    = (float2*)(ws + F_B + W_B);
  float2* est    = (float2*)(ws + F_B + 2 * W_B);
  unsigned int* dmax = (unsigned int*)(ws + F_B + 2 * W_B + E_B);

  k_init<<<12800, 256, 0, stream>>>(img0, x, PH * ZT * HW2);

  for (int it = 0; it < 3; it++){
    k_warp<<<9600, 256, 0, stream>>>(x, mvf, warped);
    hipMemsetAsync(dmax, 0, 4, stream);
    for (int p = 0; p < PH; p++){
      k_fft_row_fwd<<<960, 256, 0, stream>>>(warped, csm, F, p);
      k_fft_col    <<<960, 256, 0, stream>>>(F);
      k_sample     <<<768, 256, 0, stream>>>(F, traj, est, dmax, p);
    }
    k_weights<<<3072, 256, 0, stream>>>(est, kdata, dmax);
    for (int p = 0; p < PH; p++){
      k_fft_col_scatter<<<960, 256, 0, stream>>>(est, traj, F, p);
      k_fft_row_bwd    <<<960, 256, 0, stream>>>(F, csm, warped, p);   // warped <- gwarped
    }
    hipMemsetAsync(gdc, 0, W_B, stream);
    k_warpadj<<<240, 256, 0, stream>>>(warped, mvf, (float*)gdc);
    k_tv     <<<9600, 256, 0, stream>>>(x, warped);                    // warped <- gtv
    k_update <<<9600, 256, 0, stream>>>(x, gdc, warped, stdp);
  }
}

// Round 3
// 3128.514 us; speedup vs baseline: 1.8579x; 1.0180x over previous
//
#include <hip/hip_runtime.h>
#include <math.h>

// ---------------- problem constants ----------------
#define PH   4
#define CHN  8
#define ZT   8
#define ZE   6          // effective z slices: z in [1,7)
#define HG   320
#define WG   320
#define HW2  102400     // 320*320
#define NKP  4096
#define LSTR 321        // LDS line stride (pad +1)

constexpr float GAMMA_C = 0.1f;
constexpr float TAU_C   = 0.2f;
constexpr float EPS_C   = 0.01f;
constexpr float INV_N   = 1.0f / 786432.0f;   // PH*CHN*ZE*NKP
#define TWO_PI_F 6.28318530717958647692f

// ---------------- complex helpers ----------------
__device__ __forceinline__ float2 cmul(float2 a, float2 b){
  return make_float2(a.x*b.x - a.y*b.y, a.x*b.y + a.y*b.x);
}
__device__ __forceinline__ void cmac(float2& d, float2 a, float2 b){
  d.x = fmaf(a.x, b.x, fmaf(-a.y, b.y, d.x));
  d.y = fmaf(a.x, b.y, fmaf( a.y, b.x, d.y));
}

__device__ __forceinline__ void corners(float gy, float gx, int& y0, int& x0, int& y1, int& x1,
                                        float& w00, float& w01, float& w10, float& w11){
  float y0f = floorf(gy), x0f = floorf(gx);
  float wy = gy - y0f, wx = gx - x0f;
  y0 = (int)y0f; x0 = (int)x0f;
  y1 = min(y0 + 1, HG - 1); x1 = min(x0 + 1, WG - 1);
  w00 = (1.f - wy) * (1.f - wx);
  w01 = (1.f - wy) * wx;
  w10 = wy * (1.f - wx);
  w11 = wy * wx;
}

// ---------------- twiddles: computed once per call into global, copied to LDS per block ----
__global__ void k_twid(float2* __restrict__ w320g){
  int i = threadIdx.x;
  if (i < 320){
    float s, c;
    sincosf(-TWO_PI_F * (float)i / 320.0f, &s, &c);
    w320g[i] = make_float2(c, s);
  }
}
__device__ __forceinline__ void load_w320(float2* w320, const float2* __restrict__ w320g, int tid){
  for (int i = tid; i < 320; i += 256) w320[i] = w320g[i];
}

// ---------------- 320-pt FFT: 16 lines per block, 4-step N1=20 x N2=16 ----------------
// Forward DFT twiddles (e^{-2pi i}). The backward/transpose pass uses the SAME direction
// (formal transpose of the symmetric DFT matrix), matching JAX's bilinear VJP convention.
__device__ void fft320_lines(float2* __restrict__ ld, const float2* __restrict__ w320, int tid){
  // step 1: tasks (line, n1), 16*20 = 320 tasks. In-place safe per task (read set == write set).
  for (int task = tid; task < 320; task += 256){
    int line = task / 20;
    int n1   = task - line * 20;
    float2* L = ld + line * LSTR;
    float2 a[16];
    #pragma unroll
    for (int n2 = 0; n2 < 16; n2++) a[n2] = L[n1 + 20 * n2];
    #pragma unroll
    for (int k2 = 0; k2 < 16; k2++){
      float2 acc = make_float2(0.f, 0.f);
      #pragma unroll
      for (int n2 = 0; n2 < 16; n2++) cmac(acc, a[n2], w320[20 * ((n2 * k2) & 15)]);
      acc = cmul(acc, w320[n1 * k2]);        // inter-stage twiddle W320^{n1*k2}
      L[n1 + 20 * k2] = acc;
    }
  }
  __syncthreads();
  // step 2: tasks (line, k2), 16*16 = 256 tasks. Load->barrier->store (write set differs).
  {
    int line = tid >> 4;
    int k2   = tid & 15;
    float2* L = ld + line * LSTR;
    float2 b[20];
    #pragma unroll
    for (int n1 = 0; n1 < 20; n1++) b[n1] = L[n1 + 20 * k2];
    __syncthreads();
    #pragma unroll
    for (int k1 = 0; k1 < 20; k1++){
      float2 acc = make_float2(0.f, 0.f);
      #pragma unroll
      for (int n1 = 0; n1 < 20; n1++) cmac(acc, b[n1], w320[16 * ((n1 * k1) % 20)]);
      L[k2 + 16 * k1] = acc;
    }
  }
  __syncthreads();
}

// ---------------- kernels ----------------
__global__ __launch_bounds__(256) void k_init(const float2* __restrict__ img0, float2* __restrict__ x, int n){
  int i = blockIdx.x * 256 + threadIdx.x;
  if (i < n){
    float2 v = img0[i];
    v.x = isnan(v.x) ? 0.f : fminf(fmaxf(v.x, -3.4028235e38f), 3.4028235e38f);
    v.y = isnan(v.y) ? 0.f : fminf(fmaxf(v.y, -3.4028235e38f), 3.4028235e38f);
    x[i] = v;
  }
}

__global__ __launch_bounds__(256) void k_warp(const float2* __restrict__ x, const float* __restrict__ mvf,
                                              float2* __restrict__ warped){
  int gid = blockIdx.x * 256 + threadIdx.x;          // over PH*ZE*HW2
  int hw = gid % HW2;
  int pz = gid / HW2;
  int zz = pz % ZE, p = pz / ZE, z = zz + 1;
  int h = hw / WG, w = hw - h * WG;
  const float* mv = mvf + ((size_t)(p * 2 + 0) * ZT + z) * HW2;
  float fy = mv[hw];
  float fx = mv[(size_t)ZT * HW2 + hw];
  float gy = fminf(fmaxf((float)h + fy, 0.f), 319.f);
  float gx = fminf(fmaxf((float)w + fx, 0.f), 319.f);
  int y0, x0, y1, x1; float w00, w01, w10, w11;
  corners(gy, gx, y0, x0, y1, x1, w00, w01, w10, w11);
  const float2* xs = x + (size_t)(p * ZT + z) * HW2;
  float2 v00 = xs[y0 * WG + x0], v01 = xs[y0 * WG + x1];
  float2 v10 = xs[y1 * WG + x0], v11 = xs[y1 * WG + x1];
  float2 o;
  o.x = v00.x * w00 + v01.x * w01 + v10.x * w10 + v11.x * w11;
  o.y = v00.y * w00 + v01.y * w01 + v10.y * w10 + v11.y * w11;
  warped[gid] = o;
}

// row FFT forward, fused: in = warped*csm*(-1)^(h+w)
__global__ __launch_bounds__(256) void k_fft_row_fwd(const float2* __restrict__ warped, const float2* __restrict__ csm,
                                                     float2* __restrict__ F, const float2* __restrict__ w320g, int p){
  __shared__ float2 ld[16 * LSTR];
  __shared__ float2 w320[320];
  int tid = threadIdx.x;
  load_w320(w320, w320g, tid);
  int bid = blockIdx.x;                     // c*120 + zz*20 + rg
  int rg = bid % 20; int t = bid / 20; int zz = t % ZE; int c = t / ZE; int z = zz + 1;
  const float2* wr = warped + ((size_t)(p * ZE + zz)) * HW2 + (size_t)rg * 16 * WG;
  const float2* cs = csm + ((size_t)(c * ZT + z)) * HW2 + (size_t)rg * 16 * WG;
  for (int i = tid; i < 16 * WG; i += 256){
    int line = i / WG; int w = i - line * WG;
    float2 v = cmul(wr[i], cs[i]);
    int h = rg * 16 + line;
    float sgn = ((h + w) & 1) ? -1.f : 1.f;
    ld[line * LSTR + w] = make_float2(v.x * sgn, v.y * sgn);
  }
  __syncthreads();
  fft320_lines(ld, w320, tid);
  float2* out = F + ((size_t)(c * ZE + zz)) * HW2 + (size_t)rg * 16 * WG;
  for (int i = tid; i < 16 * WG; i += 256){
    int line = i / WG; int w = i - line * WG;
    out[i] = ld[line * LSTR + w];
  }
}

// column FFT, in place (forward pass)
__global__ __launch_bounds__(256) void k_fft_col(float2* __restrict__ F, const float2* __restrict__ w320g){
  __shared__ float2 ld[16 * LSTR];
  __shared__ float2 w320[320];
  int tid = threadIdx.x;
  load_w320(w320, w320g, tid);
  int bid = blockIdx.x;                     // slice*20 + cg, slice = c*ZE+zz
  int cg = bid % 20; int s = bid / 20;
  float2* Fs = F + (size_t)s * HW2 + cg * 16;
  for (int i = tid; i < 5120; i += 256){
    int h = i >> 4; int col = i & 15;
    ld[col * LSTR + h] = Fs[h * WG + col];
  }
  __syncthreads();
  fft320_lines(ld, w320, tid);
  for (int i = tid; i < 5120; i += 256){
    int h = i >> 4; int col = i & 15;
    Fs[h * WG + col] = ld[col * LSTR + h];
  }
}

__global__ __launch_bounds__(256) void k_sample(const float2* __restrict__ F, const float* __restrict__ traj,
                                                float2* __restrict__ est, unsigned int* __restrict__ dmax, int p){
  int gid = blockIdx.x * 256 + threadIdx.x;     // over CHN*ZE*NKP
  int k = gid & (NKP - 1);
  int t = gid >> 12;
  int zz = t % ZE; int c = t / ZE;
  float ty = traj[(p * 2 + 0) * NKP + k];
  float tx = traj[(p * 2 + 1) * NKP + k];
  float gy = fminf(fmaxf((ty / TWO_PI_F + 0.5f) * 320.f, 0.f), 319.f);
  float gx = fminf(fmaxf((tx / TWO_PI_F + 0.5f) * 320.f, 0.f), 319.f);
  int y0, x0, y1, x1; float w00, w01, w10, w11;
  corners(gy, gx, y0, x0, y1, x1, w00, w01, w10, w11);
  const float2* Fs = F + (size_t)(c * ZE + zz) * HW2;
  float2 v00 = Fs[y0 * WG + x0], v01 = Fs[y0 * WG + x1];
  float2 v10 = Fs[y1 * WG + x0], v11 = Fs[y1 * WG + x1];
  float2 e;
  e.x = v00.x * w00 + v01.x * w01 + v10.x * w10 + v11.x * w11;
  e.y = v00.y * w00 + v01.y * w01 + v10.y * w10 + v11.y * w11;
  est[((size_t)(p * CHN + c) * ZE + zz) * NKP + k] = e;
  float d2 = e.x * e.x + e.y * e.y;
  for (int off = 32; off > 0; off >>= 1) d2 = fmaxf(d2, __shfl_down(d2, off, 64));
  if ((threadIdx.x & 63) == 0) atomicMax(dmax, __float_as_uint(d2));   // d2 >= 0: uint order ok
}

// est -> cotangent: G = (w^2/N) * conj(est - y)   (conj = JAX bilinear-VJP convention)
__global__ __launch_bounds__(256) void k_weights(float2* __restrict__ est, const float2* __restrict__ kdata,
                                                 const unsigned int* __restrict__ dmax){
  int gid = blockIdx.x * 256 + threadIdx.x;     // over PH*CHN*ZE*NKP
  int k = gid & (NKP - 1);
  int t = gid >> 12;                            // (p*CHN+c)*ZE + zz
  int zz = t % ZE; int pc = t / ZE; int z = zz + 1;
  float md = sqrtf(__uint_as_float(*dmax));
  float2 e = est[gid];
  float det = sqrtf(e.x * e.x + e.y * e.y);
  float wv = 1.0f / (det / md + EPS_C);
  float sc = wv * wv * INV_N;
  float2 y = kdata[((size_t)pc * ZT + z) * NKP + k];
  est[gid] = make_float2(sc * (e.x - y.x), -sc * (e.y - y.y));
}

// backward: fused { zero-grid + k-space corner scatter (LDS atomics) + column DFT^T } per 16-col group
__global__ __launch_bounds__(256) void k_fft_col_scatter(const float2* __restrict__ G, const float* __restrict__ traj,
                                                         float2* __restrict__ F, const float2* __restrict__ w320g, int p){
  __shared__ float2 ld[16 * LSTR];
  __shared__ float2 w320[320];
  int tid = threadIdx.x;
  load_w320(w320, w320g, tid);
  int bid = blockIdx.x;                     // s*20 + cg, s = c*ZE+zz
  int cg = bid % 20; int s = bid / 20; int zz = s % ZE; int c = s / ZE;
  for (int i = tid; i < 16 * LSTR; i += 256) ld[i] = make_float2(0.f, 0.f);
  __syncthreads();
  int cbase = cg * 16;
  const float* tyb = traj + (p * 2 + 0) * NKP;
  const float* txb = traj + (p * 2 + 1) * NKP;
  const float2* Gs = G + ((size_t)(p * CHN + c) * ZE + zz) * NKP;
  for (int k = tid; k < NKP; k += 256){
    float gy = fminf(fmaxf((tyb[k] / TWO_PI_F + 0.5f) * 320.f, 0.f), 319.f);
    float gx = fminf(fmaxf((txb[k] / TWO_PI_F + 0.5f) * 320.f, 0.f), 319.f);
    int y0, x0, y1, x1; float w00, w01, w10, w11;
    corners(gy, gx, y0, x0, y1, x1, w00, w01, w10, w11);
    float2 gv = Gs[k];
    int c0 = x0 - cbase, c1 = x1 - cbase;
    if ((unsigned)c0 < 16u){
      atomicAdd(&ld[c0 * LSTR + y0].x, gv.x * w00); atomicAdd(&ld[c0 * LSTR + y0].y, gv.y * w00);
      atomicAdd(&ld[c0 * LSTR + y1].x, gv.x * w10); atomicAdd(&ld[c0 * LSTR + y1].y, gv.y * w10);
    }
    if ((unsigned)c1 < 16u){
      atomicAdd(&ld[c1 * LSTR + y0].x, gv.x * w01); atomicAdd(&ld[c1 * LSTR + y0].y, gv.y * w01);
      atomicAdd(&ld[c1 * LSTR + y1].x, gv.x * w11); atomicAdd(&ld[c1 * LSTR + y1].y, gv.y * w11);
    }
  }
  __syncthreads();
  fft320_lines(ld, w320, tid);
  float2* Fs = F + (size_t)s * HW2 + cbase;
  for (int i = tid; i < 5120; i += 256){
    int h = i >> 4; int col = i & 15;
    Fs[h * WG + col] = ld[col * LSTR + h];
  }
}

// transpose row pass, fused epilogue: *(-1)^(h+w), *csm (NO conj: formal transpose), sum over coils
__global__ __launch_bounds__(256) void k_fft_row_bwd(const float2* __restrict__ F, const float2* __restrict__ csm,
                                                     float2* __restrict__ gwarped, const float2* __restrict__ w320g, int p){
  __shared__ float2 ld[16 * LSTR];
  __shared__ float2 w320[320];
  int tid = threadIdx.x;
  load_w320(w320, w320g, tid);
  int bid = blockIdx.x;                    // zz*160 + rp
  int rp = bid % 160; int zz = bid / 160; int z = zz + 1;
  for (int i = tid; i < 16 * WG; i += 256){
    int line = i / WG; int w = i - line * WG;
    int c = line & 7; int hh = line >> 3;
    ld[line * LSTR + w] = F[((size_t)(c * ZE + zz)) * HW2 + (size_t)(rp * 2 + hh) * WG + w];
  }
  __syncthreads();
  fft320_lines(ld, w320, tid);
  for (int i = tid; i < 2 * WG; i += 256){
    int hh = i / WG; int w = i - hh * WG;
    int h = rp * 2 + hh;
    float2 acc = make_float2(0.f, 0.f);
    #pragma unroll
    for (int c = 0; c < 8; c++){
      float2 u  = ld[(hh * 8 + c) * LSTR + w];
      float2 cv = csm[((size_t)(c * ZT + z)) * HW2 + (size_t)h * WG + w];
      cmac(acc, u, cv);
    }
    float sgn = ((h + w) & 1) ? -1.f : 1.f;
    gwarped[((size_t)(p * ZE + zz)) * HW2 + (size_t)h * WG + w] = make_float2(acc.x * sgn, acc.y * sgn);
  }
}

// LDS-tiled warp adjoint: block owns TR source rows; scatters into [r0-HA, r0+TR+HA) LDS tile,
// then flushes with coalesced global atomics. Out-of-window targets (P ~ 6e-5) -> direct atomics.
// 512 threads, 80 KB LDS -> 2 WG/CU (16 waves/CU).
#define TR 16
#define HA 8
#define LROWS (TR + 2*HA)   // 32 rows; LDS = 32*320*2*4B = 81920 B
__global__ __launch_bounds__(512) void k_warpadj(const float2* __restrict__ gw, const float* __restrict__ mvf,
                                                 float* __restrict__ gdc){
  __shared__ float lt[LROWS * WG * 2];
  int tid = threadIdx.x;
  int bid = blockIdx.x;                    // pz*20 + tile
  int tile = bid % 20; int pz = bid / 20;
  int zz = pz % ZE, p = pz / ZE, z = zz + 1;
  int r0 = tile * TR;
  for (int i = tid; i < LROWS * WG * 2; i += 512) lt[i] = 0.f;
  __syncthreads();
  const float* mvy = mvf + ((size_t)(p * 2 + 0) * ZT + z) * HW2;
  const float* mvx = mvy + (size_t)ZT * HW2;
  const float2* g = gw + (size_t)pz * HW2;
  float* gs = gdc + (size_t)pz * HW2 * 2;
  const int lo = r0 - HA;
  for (int i = tid; i < TR * WG; i += 512){
    int hh = i / WG;
    int h = r0 + hh; int w = i - hh * WG;
    int hw = h * WG + w;
    float fy = mvy[hw];
    float fx = mvx[hw];
    float gy = fminf(fmaxf((float)h + fy, 0.f), 319.f);
    float gx = fminf(fmaxf((float)w + fx, 0.f), 319.f);
    int y0, x0, y1, x1; float w00, w01, w10, w11;
    corners(gy, gx, y0, x0, y1, x1, w00, w01, w10, w11);
    float2 gv = g[hw];
    int ry0 = y0 - lo, ry1 = y1 - lo;
    if ((unsigned)ry0 < (unsigned)LROWS){
      atomicAdd(&lt[(ry0 * WG + x0) * 2 + 0], gv.x * w00); atomicAdd(&lt[(ry0 * WG + x0) * 2 + 1], gv.y * w00);
      atomicAdd(&lt[(ry0 * WG + x1) * 2 + 0], gv.x * w01); atomicAdd(&lt[(ry0 * WG + x1) * 2 + 1], gv.y * w01);
    } else {
      atomicAdd(&gs[(y0 * WG + x0) * 2 + 0], gv.x * w00); atomicAdd(&gs[(y0 * WG + x0) * 2 + 1], gv.y * w00);
      atomicAdd(&gs[(y0 * WG + x1) * 2 + 0], gv.x * w01); atomicAdd(&gs[(y0 * WG + x1) * 2 + 1], gv.y * w01);
    }
    if ((unsigned)ry1 < (unsigned)LROWS){
      atomicAdd(&lt[(ry1 * WG + x0) * 2 + 0], gv.x * w10); atomicAdd(&lt[(ry1 * WG + x0) * 2 + 1], gv.y * w10);
      atomicAdd(&lt[(ry1 * WG + x1) * 2 + 0], gv.x * w11); atomicAdd(&lt[(ry1 * WG + x1) * 2 + 1], gv.y * w11);
    } else {
      atomicAdd(&gs[(y1 * WG + x0) * 2 + 0], gv.x * w10); atomicAdd(&gs[(y1 * WG + x0) * 2 + 1], gv.y * w10);
      atomicAdd(&gs[(y1 * WG + x1) * 2 + 0], gv.x * w11); atomicAdd(&gs[(y1 * WG + x1) * 2 + 1], gv.y * w11);
    }
  }
  __syncthreads();
  for (int i = tid; i < LROWS * WG; i += 512){
    int rr = i / WG; int w = i - rr * WG;
    int h = lo + rr;
    if ((unsigned)h < (unsigned)HG){
      float vx = lt[i * 2 + 0], vy = lt[i * 2 + 1];
      if (vx != 0.f) atomicAdd(&gs[(h * WG + w) * 2 + 0], vx);
      if (vy != 0.f) atomicAdd(&gs[(h * WG + w) * 2 + 1], vy);
    }
  }
}

// TV gradient (natural real-pair grad), stored CONJUGATED to match jax.grad convention
__global__ __launch_bounds__(256) void k_tv(const float2* __restrict__ x, float2* __restrict__ gtv){
  int gid = blockIdx.x * 256 + threadIdx.x;     // PH*ZE*HW2
  int hw = gid % HW2;
  int pz = gid / HW2;
  int zz = pz % ZE, p = pz / ZE, z = zz + 1;
  int h = hw / WG, w = hw - h * WG;
  const float2* xs = x + (size_t)(p * ZT + z) * HW2;
  float2 xc = xs[hw];
  float tre = 0.f, tim = 0.f;
  if (h > 0){
    float2 n = xs[hw - WG];
    float dr = xc.x - n.x, di = xc.y - n.y;
    float r = sqrtf(dr * dr + di * di + 1e-8f);
    tre += dr / r; tim += di / r;
  }
  if (h < HG - 1){
    float2 n = xs[hw + WG];
    float dr = n.x - xc.x, di = n.y - xc.y;
    float r = sqrtf(dr * dr + di * di + 1e-8f);
    tre -= dr / r; tim -= di / r;
  }
  if (w > 0){
    float2 n = xs[hw - 1];
    float dr = xc.x - n.x, di = xc.y - n.y;
    float r = sqrtf(dr * dr + di * di + 1e-8f);
    tre += dr / r; tim += di / r;
  }
  if (w < WG - 1){
    float2 n = xs[hw + 1];
    float dr = n.x - xc.x, di = n.y - xc.y;
    float r = sqrtf(dr * dr + di * di + 1e-8f);
    tre -= dr / r; tim -= di / r;
  }
  gtv[gid] = make_float2(tre, -tim);
}

__global__ __launch_bounds__(256) void k_update(float2* __restrict__ x, const float2* __restrict__ gdc,
                                                const float2* __restrict__ gtv, const float* __restrict__ stdp){
  int gid = blockIdx.x * 256 + threadIdx.x;     // PH*ZE*HW2
  int hw = gid % HW2;
  int pz = gid / HW2;
  int zz = pz % ZE, p = pz / ZE;
  float s = stdp[0];
  size_t xi = (size_t)(p * ZT + zz + 1) * HW2 + hw;
  float2 xv = x[xi];
  float2 gd = gdc[gid], gt = gtv[gid];
  xv.x -= GAMMA_C * gd.x + TAU_C * s * gt.x;
  xv.y -= GAMMA_C * gd.y + TAU_C * s * gt.y;
  x[xi] = xv;
}

// ---------------- host ----------------
extern "C" void kernel_launch(void* const* d_in, const int* in_sizes, int n_in,
                              void* d_out, int out_size, void* d_ws, size_t ws_size,
                              hipStream_t stream) {
  const float2* kdata = (const float2*)d_in[0];   // (PH,CHN,ZT,NK) complex
  const float*  traj  = (const float*) d_in[1];   // (PH,2,NK)
  const float2* img0  = (const float2*)d_in[2];   // (PH,ZT,H,W) complex
  const float*  mvf   = (const float*) d_in[3];   // (PH,2,ZT,H,W)
  const float2* csm   = (const float2*)d_in[4];   // (CHN,ZT,H,W) complex
  const float*  stdp  = (const float*) d_in[5];   // (1,)
  float2* x = (float2*)d_out;                     // x lives in d_out (same layout as output)

  // workspace layout (bytes): total ~85 MB
  char* ws = (char*)d_ws;
  const size_t F_B  = (size_t)CHN * ZE * HW2 * 8;        // 39,321,600
  const size_t W_B  = (size_t)PH * ZE * HW2 * 8;         // 19,660,800
  const size_t E_B  = (size_t)PH * CHN * ZE * NKP * 8;   //  6,291,456
  float2* F      = (float2*)(ws);
  float2* warped = (float2*)(ws + F_B);                  // also reused for gwarped, then gtv
  float2* gdc    = (float2*)(ws + F_B + W_B);
  float2* est    = (float2*)(ws + F_B + 2 * W_B);
  unsigned int* dmax = (unsigned int*)(ws + F_B + 2 * W_B + E_B);
  float2* w320g  = (float2*)(ws + F_B + 2 * W_B + E_B + 256);

  k_init<<<12800, 256, 0, stream>>>(img0, x, PH * ZT * HW2);
  k_twid<<<1, 320, 0, stream>>>(w320g);

  for (int it = 0; it < 3; it++){
    k_warp<<<9600, 256, 0, stream>>>(x, mvf, warped);
    hipMemsetAsync(dmax, 0, 4, stream);
    for (int p = 0; p < PH; p++){
      k_fft_row_fwd<<<960, 256, 0, stream>>>(warped, csm, F, w320g, p);
      k_fft_col    <<<960, 256, 0, stream>>>(F, w320g);
      k_sample     <<<768, 256, 0, stream>>>(F, traj, est, dmax, p);
    }
    k_weights<<<3072, 256, 0, stream>>>(est, kdata, dmax);
    for (int p = 0; p < PH; p++){
      k_fft_col_scatter<<<960, 256, 0, stream>>>(est, traj, F, w320g, p);
      k_fft_row_bwd    <<<960, 256, 0, stream>>>(F, csm, warped, w320g, p);   // warped <- gwarped
    }
    hipMemsetAsync(gdc, 0, W_B, stream);
    k_warpadj<<<480, 512, 0, stream>>>(warped, mvf, (float*)gdc);
    k_tv     <<<9600, 256, 0, stream>>>(x, warped);                    // warped <- gtv
    k_update <<<9600, 256, 0, stream>>>(x, gdc, warped, stdp);
  }
}